// Round 1
// baseline (370.307 us; speedup 1.0000x reference)
//
#include <hip/hip_runtime.h>
#include <stdint.h>

typedef unsigned short u16;
typedef __attribute__((ext_vector_type(4))) float f32x4;
typedef __attribute__((ext_vector_type(8))) short bf16x8;

#define MFMA16(a,b,c) __builtin_amdgcn_mfma_f32_16x16x32_bf16((a),(b),(c),0,0,0)
#define LOG2E 1.44269504088896340736f

__device__ __forceinline__ u16 f2bf(float f){
  union { float f; uint32_t u; } v; v.f = f;
  uint32_t r = v.u + 0x7fffu + ((v.u >> 16) & 1u);
  return (u16)(r >> 16);
}

__device__ __forceinline__ void gload16(const void* g, void* l){
  __builtin_amdgcn_global_load_lds(
      (const __attribute__((address_space(1))) void*)g,
      (__attribute__((address_space(3))) void*)l, 16, 0, 0);
}

// ---------------- pre-pass ----------------
__global__ __launch_bounds__(256) void cvt_bf16_k(const float* __restrict__ in, u16* __restrict__ out){
  int i = blockIdx.x*256 + threadIdx.x;
  float4 v = reinterpret_cast<const float4*>(in)[i];
  ushort4 o;
  o.x = f2bf(v.x); o.y = f2bf(v.y); o.z = f2bf(v.z); o.w = f2bf(v.w);
  reinterpret_cast<ushort4*>(out)[i] = o;
}

// in [R][C] f32 -> out [C][R] bf16
__global__ __launch_bounds__(256) void transpose_cvt_k(const float* __restrict__ in, u16* __restrict__ out,
                                                       int R, int C){
  __shared__ float tile[64][65];
  int c0 = blockIdx.x*64, r0 = blockIdx.y*64;
  int t = threadIdx.x; int cc = t & 63, rr = t >> 6;
  #pragma unroll
  for (int i=0;i<16;++i){ int r = rr + i*4; tile[r][cc] = in[(size_t)(r0+r)*C + c0+cc]; }
  __syncthreads();
  #pragma unroll
  for (int i=0;i<16;++i){ int r = rr + i*4; out[(size_t)(c0+r)*R + r0+cc] = f2bf(tile[cc][r]); }
}

// ---------------- GEMM core: C[128x128] = A[128xK] * Bt[128xK]^T, K=1024 ----------------
__device__ __forceinline__ void gemm_core(const u16* __restrict__ A, const u16* __restrict__ Bt,
                                          int bm, int bn, char* lds, f32x4 (&acc)[4][4]){
  const int K = 1024;
  int tid = threadIdx.x, w = tid >> 6, l = tid & 63;
  int lrow = l & 15, lg = l >> 4;
  int wm = w >> 1, wn = w & 1;
  const u16* aSrc = A + (size_t)(bm*128 + w*32 + (l>>3))*K + (((l&7)^(l>>3))<<3);
  const u16* bSrc = Bt + (size_t)(bn*128 + w*32 + (l>>3))*K + (((l&7)^(l>>3))<<3);
  char* aDst = lds + w*4096;
  char* bDst = lds + 16384 + w*4096;
  for (int kk = 0; kk < 16; ++kk){
    __syncthreads();
    #pragma unroll
    for (int i=0;i<4;++i) gload16(aSrc + (size_t)i*8*K + kk*64, aDst + i*1024);
    #pragma unroll
    for (int i=0;i<4;++i) gload16(bSrc + (size_t)i*8*K + kk*64, bDst + i*1024);
    __syncthreads();
    #pragma unroll
    for (int ks=0; ks<2; ++ks){
      bf16x8 af[4], bfv[4];
      #pragma unroll
      for (int m=0;m<4;++m){
        int row = wm*64 + m*16 + lrow;
        af[m] = *reinterpret_cast<const bf16x8*>(lds + row*128 + (((ks*4+lg)^(row&7))<<4));
      }
      #pragma unroll
      for (int n=0;n<4;++n){
        int row = wn*64 + n*16 + lrow;
        bfv[n] = *reinterpret_cast<const bf16x8*>(lds + 16384 + row*128 + (((ks*4+lg)^(row&7))<<4));
      }
      #pragma unroll
      for (int m=0;m<4;++m){
        #pragma unroll
        for (int n=0;n<4;++n)
          acc[m][n] = MFMA16(af[m], bfv[n], acc[m][n]);
      }
    }
  }
}

// ---------------- GEMM1: x_bf16 @ w_qkvT^T -> scatter q,k,vT ----------------
__global__ __launch_bounds__(256,2) void gemm_qkv_k(const u16* __restrict__ A, const u16* __restrict__ Bt,
                                                    u16* __restrict__ qw, u16* __restrict__ kw,
                                                    u16* __restrict__ vtw){
  __shared__ __align__(16) char lds[32768];
  const f32x4 zero4 = {0.f, 0.f, 0.f, 0.f};
  f32x4 acc[4][4];
  #pragma unroll
  for (int m=0;m<4;++m){
    #pragma unroll
    for (int n=0;n<4;++n) acc[m][n] = zero4;
  }
  int bn = blockIdx.x, bm = blockIdx.y;
  gemm_core(A, Bt, bm, bn, lds, acc);
  int tid = threadIdx.x, w = tid >> 6, l = tid & 63;
  int lrow = l & 15, lg = l >> 4;
  int wm = w >> 1, wn = w & 1;
  #pragma unroll
  for (int n=0;n<4;++n){
    int gcol = bn*128 + wn*64 + n*16 + lrow;        // 0..3071
    int which = gcol >> 10;
    int inner = gcol & 1023;
    int h = inner >> 6, d = inner & 63;
    #pragma unroll
    for (int m=0;m<4;++m){
      #pragma unroll
      for (int r=0;r<4;++r){
        int grow = bm*128 + wm*64 + m*16 + lg*4 + r; // b*S + s
        int b = grow >> 11, sq = grow & 2047;
        float v = acc[m][n][r];
        if (which == 0)
          qw[((size_t)((b*16 + h)*2048 + sq))*64 + d] = f2bf(v * 0.125f);
        else if (which == 1)
          kw[((size_t)((b*16 + h)*2048 + sq))*64 + d] = f2bf(v);
        else
          vtw[((size_t)((b*16 + h)*64 + d))*2048 + sq] = f2bf(v);
      }
    }
  }
}

// ---------------- flash attention (causal) ----------------
__global__ __launch_bounds__(256,2) void attn_k(const u16* __restrict__ Qw, const u16* __restrict__ Kw,
                                                const u16* __restrict__ VTw, u16* __restrict__ Ow){
  __shared__ __align__(16) char lds[32768];
  char* Qs = lds;
  char* Ks = lds + 8192;
  char* Vs = lds + 16384;
  const f32x4 zero4 = {0.f, 0.f, 0.f, 0.f};
  int qb = blockIdx.x, bh = blockIdx.y;
  int tid = threadIdx.x, w = tid >> 6, l = tid & 63;
  int lrow = l & 15, lg = l >> 4;
  char* Pw = lds + 24576 + w*2048;
  const size_t base = (size_t)bh * (2048*64);
  // stage Q tile [64][64]
  {
    const u16* qsrc = Qw + base + (size_t)(qb*64 + w*16 + (l>>3))*64 + (((l&7)^(l>>3))<<3);
    gload16(qsrc,       Qs + w*2048);
    gload16(qsrc + 512, Qs + w*2048 + 1024);
  }
  __syncthreads();
  bf16x8 qa[2];
  {
    int row = w*16 + lrow;
    qa[0] = *reinterpret_cast<const bf16x8*>(Qs + row*128 + (((0+lg)^(row&7))<<4));
    qa[1] = *reinterpret_cast<const bf16x8*>(Qs + row*128 + (((4+lg)^(row&7))<<4));
  }
  float m_s[4] = {-1e30f,-1e30f,-1e30f,-1e30f};
  float l_s[4] = {0.f,0.f,0.f,0.f};
  f32x4 o[4];
  #pragma unroll
  for (int f=0;f<4;++f) o[f] = zero4;
  const u16* ksrc = Kw + base + (size_t)(w*16 + (l>>3))*64 + (((l&7)^(l>>3))<<3);
  const u16* vsrc = VTw + base + (size_t)(w*16 + (l>>3))*2048 + (((l&7)^(l>>3))<<3);
  const int nt = qb + 1;
  for (int t = 0; t < nt; ++t){
    const int kv0 = t*64;
    __syncthreads();
    gload16(ksrc + (size_t)kv0*64,       Ks + w*2048);
    gload16(ksrc + (size_t)kv0*64 + 512, Ks + w*2048 + 1024);
    gload16(vsrc + kv0,                  Vs + w*2048);
    gload16(vsrc + kv0 + 8*2048,         Vs + w*2048 + 1024);
    __syncthreads();
    // S = Q K^T (scale folded into Q)
    f32x4 s[4];
    #pragma unroll
    for (int f=0;f<4;++f){
      f32x4 a = zero4;
      #pragma unroll
      for (int ks=0; ks<2; ++ks){
        int row = f*16 + lrow;
        bf16x8 kb = *reinterpret_cast<const bf16x8*>(Ks + row*128 + (((ks*4+lg)^(row&7))<<4));
        a = MFMA16(qa[ks], kb, a);
      }
      s[f] = a;
    }
    if (t == nt-1){
      int qg = qb*64 + w*16 + lg*4;
      #pragma unroll
      for (int f=0;f<4;++f){
        int kvg = kv0 + f*16 + lrow;
        #pragma unroll
        for (int r=0;r<4;++r)
          if (kvg > qg + r) s[f][r] += -1250.0f;   // (-10000)*scale, matches reference
      }
    }
    float corr[4];
    #pragma unroll
    for (int r=0;r<4;++r){
      float mx = fmaxf(fmaxf(s[0][r], s[1][r]), fmaxf(s[2][r], s[3][r]));
      mx = fmaxf(mx, __shfl_xor(mx, 1));
      mx = fmaxf(mx, __shfl_xor(mx, 2));
      mx = fmaxf(mx, __shfl_xor(mx, 4));
      mx = fmaxf(mx, __shfl_xor(mx, 8));
      float mn = fmaxf(m_s[r], mx);
      float c = exp2f((m_s[r] - mn)*LOG2E);
      float rs = 0.f;
      #pragma unroll
      for (int f=0;f<4;++f){
        float p = exp2f((s[f][r] - mn)*LOG2E);
        s[f][r] = p; rs += p;
      }
      rs += __shfl_xor(rs, 1);
      rs += __shfl_xor(rs, 2);
      rs += __shfl_xor(rs, 4);
      rs += __shfl_xor(rs, 8);
      l_s[r] = l_s[r]*c + rs;
      m_s[r] = mn;
      corr[r] = c;
    }
    #pragma unroll
    for (int f=0;f<4;++f){
      #pragma unroll
      for (int r=0;r<4;++r) o[f][r] *= corr[r];
    }
    // P -> LDS (per-wave region, XOR swizzled rows)
    #pragma unroll
    for (int f=0;f<4;++f){
      #pragma unroll
      for (int r=0;r<4;++r){
        int prow = lg*4 + r;
        int byt = (prow*128 + (f*16 + lrow)*2) ^ ((prow&7)<<4);
        *reinterpret_cast<u16*>(Pw + byt) = f2bf(s[f][r]);
      }
    }
    bf16x8 pa[2];
    pa[0] = *reinterpret_cast<const bf16x8*>(Pw + lrow*128 + (((0+lg)^(lrow&7))<<4));
    pa[1] = *reinterpret_cast<const bf16x8*>(Pw + lrow*128 + (((4+lg)^(lrow&7))<<4));
    #pragma unroll
    for (int f=0;f<4;++f){
      #pragma unroll
      for (int ks=0; ks<2; ++ks){
        int row = f*16 + lrow;
        bf16x8 vb = *reinterpret_cast<const bf16x8*>(Vs + row*128 + (((ks*4+lg)^(row&7))<<4));
        o[f] = MFMA16(pa[ks], vb, o[f]);
      }
    }
  }
  int b = bh >> 4, h = bh & 15;
  #pragma unroll
  for (int r=0;r<4;++r) l_s[r] = 1.0f / l_s[r];
  #pragma unroll
  for (int f=0;f<4;++f){
    #pragma unroll
    for (int r=0;r<4;++r){
      int sq = qb*64 + w*16 + lg*4 + r;
      Ow[((size_t)(b*2048 + sq))*1024 + h*64 + f*16 + lrow] = f2bf(o[f][r] * l_s[r]);
    }
  }
}

// ---------------- GEMM2: attn @ w_outT^T + bias -> f32 out ----------------
__global__ __launch_bounds__(256,2) void gemm_out_k(const u16* __restrict__ A, const u16* __restrict__ Bt,
                                                    const float* __restrict__ bias_p, float* __restrict__ out){
  __shared__ __align__(16) char lds[32768];
  const f32x4 zero4 = {0.f, 0.f, 0.f, 0.f};
  f32x4 acc[4][4];
  #pragma unroll
  for (int m=0;m<4;++m){
    #pragma unroll
    for (int n=0;n<4;++n) acc[m][n] = zero4;
  }
  int bn = blockIdx.x, bm = blockIdx.y;
  gemm_core(A, Bt, bm, bn, lds, acc);
  int tid = threadIdx.x, w = tid >> 6, l = tid & 63;
  int lrow = l & 15, lg = l >> 4;
  int wm = w >> 1, wn = w & 1;
  #pragma unroll
  for (int n=0;n<4;++n){
    int gcol = bn*128 + wn*64 + n*16 + lrow;
    float bias = bias_p[gcol];
    #pragma unroll
    for (int m=0;m<4;++m){
      #pragma unroll
      for (int r=0;r<4;++r){
        int grow = bm*128 + wm*64 + m*16 + lg*4 + r;
        out[(size_t)grow*1024 + gcol] = acc[m][n][r] + bias;
      }
    }
  }
}

extern "C" void kernel_launch(void* const* d_in, const int* in_sizes, int n_in,
                              void* d_out, int out_size, void* d_ws, size_t ws_size,
                              hipStream_t stream){
  (void)in_sizes; (void)n_in; (void)out_size; (void)ws_size;
  const float* x     = (const float*)d_in[0];
  const float* w_qkv = (const float*)d_in[1];
  const float* w_out = (const float*)d_in[2];
  const float* b_out = (const float*)d_in[3];
  float* out = (float*)d_out;
  char* ws = (char*)d_ws;
  u16* xb    = (u16*)(ws + 0);          // 8192*1024 bf16      = 16 MiB
  u16* wqkvT = (u16*)(ws + 16777216);   // 3072*1024 bf16      =  6 MiB
  u16* woutT = (u16*)(ws + 23068672);   // 1024*1024 bf16      =  2 MiB
  u16* qw    = (u16*)(ws + 25165824);   // [4,16,2048,64] bf16 = 16 MiB
  u16* kw    = (u16*)(ws + 41943040);   // [4,16,2048,64] bf16 = 16 MiB
  u16* vtw   = (u16*)(ws + 58720256);   // [4,16,64,2048] bf16 = 16 MiB
  u16* attn  = (u16*)(ws + 75497472);   // [4,2048,1024] bf16  = 16 MiB

  cvt_bf16_k<<<8192, 256, 0, stream>>>(x, xb);                           // 8.39M elems /4
  transpose_cvt_k<<<dim3(48,16), 256, 0, stream>>>(w_qkv, wqkvT, 1024, 3072);
  transpose_cvt_k<<<dim3(16,16), 256, 0, stream>>>(w_out, woutT, 1024, 1024);
  gemm_qkv_k<<<dim3(24,64), 256, 0, stream>>>(xb, wqkvT, qw, kw, vtw);
  attn_k<<<dim3(32,64), 256, 0, stream>>>(qw, kw, vtw, attn);
  gemm_out_k<<<dim3(8,64), 256, 0, stream>>>(attn, woutT, b_out, out);
}

// Round 2
// 302.741 us; speedup vs baseline: 1.2232x; 1.2232x over previous
//
#include <hip/hip_runtime.h>
#include <stdint.h>

typedef unsigned short u16;
typedef uint32_t u32;
typedef __attribute__((ext_vector_type(4))) float f32x4;
typedef __attribute__((ext_vector_type(16))) float f32x16;
typedef __attribute__((ext_vector_type(8))) short bf16x8;
typedef __attribute__((ext_vector_type(4))) u32 u32x4;

#define MFMA16(a,b,c) __builtin_amdgcn_mfma_f32_16x16x32_bf16((a),(b),(c),0,0,0)
#define MFMA32(a,b,c) __builtin_amdgcn_mfma_f32_32x32x16_bf16((a),(b),(c),0,0,0)
#define QSCALE 0.18033688011112042f   /* 0.125 * log2(e) */
#define MASKB  -1803.3688011112042f   /* -10000 * QSCALE */

__device__ __forceinline__ u16 f2bf(float f){
  union { float f; uint32_t u; } v; v.f = f;
  uint32_t r = v.u + 0x7fffu + ((v.u >> 16) & 1u);
  return (u16)(r >> 16);
}

__device__ __forceinline__ u32 cvtpk(float lo, float hi){
  u32 r;
  asm volatile("v_cvt_pk_bf16_f32 %0, %1, %2" : "=v"(r) : "v"(lo), "v"(hi));
  return r;
}

union U4 { u32x4 u; bf16x8 b; };
__device__ __forceinline__ bf16x8 mkfrag(u32 a, u32 b, u32 c, u32 d){
  U4 x; x.u = (u32x4){a,b,c,d}; return x.b;
}

__device__ __forceinline__ void gload16(const void* g, void* l){
  __builtin_amdgcn_global_load_lds(
      (const __attribute__((address_space(1))) void*)g,
      (__attribute__((address_space(3))) void*)l, 16, 0, 0);
}

// ---------------- pre-pass ----------------
__global__ __launch_bounds__(256) void cvt_bf16_k(const float* __restrict__ in, u16* __restrict__ out){
  int i = blockIdx.x*256 + threadIdx.x;
  float4 v = reinterpret_cast<const float4*>(in)[i];
  ushort4 o;
  o.x = f2bf(v.x); o.y = f2bf(v.y); o.z = f2bf(v.z); o.w = f2bf(v.w);
  reinterpret_cast<ushort4*>(out)[i] = o;
}

// in [R][C] f32 -> out [C][R] bf16
__global__ __launch_bounds__(256) void transpose_cvt_k(const float* __restrict__ in, u16* __restrict__ out,
                                                       int R, int C){
  __shared__ float tile[64][65];
  int c0 = blockIdx.x*64, r0 = blockIdx.y*64;
  int t = threadIdx.x; int cc = t & 63, rr = t >> 6;
  #pragma unroll
  for (int i=0;i<16;++i){ int r = rr + i*4; tile[r][cc] = in[(size_t)(r0+r)*C + c0+cc]; }
  __syncthreads();
  #pragma unroll
  for (int i=0;i<16;++i){ int r = rr + i*4; out[(size_t)(c0+r)*R + r0+cc] = f2bf(tile[cc][r]); }
}

// ---------------- GEMM core: C[128x128] = A[128xK] * Bt[128xK]^T, K=1024 ----------------
__device__ __forceinline__ void gemm_core(const u16* __restrict__ A, const u16* __restrict__ Bt,
                                          int bm, int bn, char* lds, f32x4 (&acc)[4][4]){
  const int K = 1024;
  int tid = threadIdx.x, w = tid >> 6, l = tid & 63;
  int lrow = l & 15, lg = l >> 4;
  int wm = w >> 1, wn = w & 1;
  const u16* aSrc = A + (size_t)(bm*128 + w*32 + (l>>3))*K + (((l&7)^(l>>3))<<3);
  const u16* bSrc = Bt + (size_t)(bn*128 + w*32 + (l>>3))*K + (((l&7)^(l>>3))<<3);
  char* aDst = lds + w*4096;
  char* bDst = lds + 16384 + w*4096;
  for (int kk = 0; kk < 16; ++kk){
    __syncthreads();
    #pragma unroll
    for (int i=0;i<4;++i) gload16(aSrc + (size_t)i*8*K + kk*64, aDst + i*1024);
    #pragma unroll
    for (int i=0;i<4;++i) gload16(bSrc + (size_t)i*8*K + kk*64, bDst + i*1024);
    __syncthreads();
    #pragma unroll
    for (int ks=0; ks<2; ++ks){
      bf16x8 af[4], bfv[4];
      #pragma unroll
      for (int m=0;m<4;++m){
        int row = wm*64 + m*16 + lrow;
        af[m] = *reinterpret_cast<const bf16x8*>(lds + row*128 + (((ks*4+lg)^(row&7))<<4));
      }
      #pragma unroll
      for (int n=0;n<4;++n){
        int row = wn*64 + n*16 + lrow;
        bfv[n] = *reinterpret_cast<const bf16x8*>(lds + 16384 + row*128 + (((ks*4+lg)^(row&7))<<4));
      }
      #pragma unroll
      for (int m=0;m<4;++m){
        #pragma unroll
        for (int n=0;n<4;++n)
          acc[m][n] = MFMA16(af[m], bfv[n], acc[m][n]);
      }
    }
  }
}

// ---------------- GEMM1: x_bf16 @ w_qkvT^T -> scatter q,k,vT ----------------
__global__ __launch_bounds__(256,2) void gemm_qkv_k(const u16* __restrict__ A, const u16* __restrict__ Bt,
                                                    u16* __restrict__ qw, u16* __restrict__ kw,
                                                    u16* __restrict__ vtw){
  __shared__ __align__(16) char lds[32768];
  const f32x4 zero4 = {0.f, 0.f, 0.f, 0.f};
  f32x4 acc[4][4];
  #pragma unroll
  for (int m=0;m<4;++m){
    #pragma unroll
    for (int n=0;n<4;++n) acc[m][n] = zero4;
  }
  int bn = blockIdx.x, bm = blockIdx.y;
  gemm_core(A, Bt, bm, bn, lds, acc);
  int tid = threadIdx.x, w = tid >> 6, l = tid & 63;
  int lrow = l & 15, lg = l >> 4;
  int wm = w >> 1, wn = w & 1;
  #pragma unroll
  for (int n=0;n<4;++n){
    int gcol = bn*128 + wn*64 + n*16 + lrow;        // 0..3071
    int which = gcol >> 10;
    int inner = gcol & 1023;
    int h = inner >> 6, d = inner & 63;
    #pragma unroll
    for (int m=0;m<4;++m){
      #pragma unroll
      for (int r=0;r<4;++r){
        int grow = bm*128 + wm*64 + m*16 + lg*4 + r; // b*S + s
        int b = grow >> 11, sq = grow & 2047;
        float v = acc[m][n][r];
        if (which == 0)
          qw[((size_t)((b*16 + h)*2048 + sq))*64 + d] = f2bf(v * QSCALE);
        else if (which == 1)
          kw[((size_t)((b*16 + h)*2048 + sq))*64 + d] = f2bf(v);
        else
          vtw[((size_t)((b*16 + h)*64 + d))*2048 + sq] = f2bf(v);
      }
    }
  }
}

// ---------------- flash attention v2: 4 waves x 32 q-rows, swapped 32x32 MFMA ----------------
__global__ __launch_bounds__(256) void attn_k(const u16* __restrict__ Qw, const u16* __restrict__ Kw,
                                              const u16* __restrict__ VTw, u16* __restrict__ Ow){
  __shared__ __align__(16) char lds[32768];   // 2 x (K 8KB + V 8KB)
  const int qb = blockIdx.x;                  // 16 q-blocks of 128 rows
  const int bh = blockIdx.y;
  const int tid = threadIdx.x, w = tid >> 6, l = tid & 63;
  const int lo = l & 31, hi = l >> 5;
  const size_t base = (size_t)bh * (2048*64);
  const int qw0 = qb*128 + w*32;
  const int q_l = qw0 + lo;

  bf16x8 qa[4];
  {
    const u16* qsrc = Qw + base + (size_t)q_l*64 + hi*8;
    #pragma unroll
    for (int ks=0; ks<4; ++ks) qa[ks] = *reinterpret_cast<const bf16x8*>(qsrc + ks*16);
  }

  const int srow = tid >> 3;                 // 0..31
  const int scs  = (tid & 7) ^ (srow & 7);   // pre-swizzled 16B slot
  const u16* kS = Kw  + base + (size_t)srow*64   + scs*8;
  const u16* vS = VTw + base + (size_t)srow*2048 + scs*8;

  f32x16 acc0 = {0,0,0,0,0,0,0,0,0,0,0,0,0,0,0,0};
  f32x16 acc1 = {0,0,0,0,0,0,0,0,0,0,0,0,0,0,0,0};
  float m_s = -1e30f, l_s = 0.f;

  const int nt = qb*2 + 2;

  #define STAGE(buf, t) do { \
    int kv0_ = (t)*64; \
    gload16(kS + (size_t)kv0_*64,        lds + (buf)*16384 +     0 + w*1024); \
    gload16(kS + (size_t)(kv0_+32)*64,   lds + (buf)*16384 +  4096 + w*1024); \
    gload16(vS + kv0_,                   lds + (buf)*16384 +  8192 + w*1024); \
    gload16(vS + kv0_ + (size_t)32*2048, lds + (buf)*16384 + 12288 + w*1024); \
  } while(0)

  STAGE(0, 0);
  __syncthreads();

  int cur = 0;
  for (int t = 0; t < nt; ++t){
    if (t+1 < nt){
      if (cur) STAGE(0, t+1); else STAGE(1, t+1);
    }
    const int kv0 = t*64;
    if (kv0 < qw0 + 32){
      const char* KB = lds + cur*16384;
      const char* VB = KB + 8192;
      #pragma unroll
      for (int t2=0; t2<2; ++t2){
        const int kvs0 = kv0 + t2*32;
        if (kvs0 < qw0 + 32){
          f32x16 s = {0,0,0,0,0,0,0,0,0,0,0,0,0,0,0,0};
          #pragma unroll
          for (int ks=0; ks<4; ++ks){
            int krow = t2*32 + lo;
            bf16x8 kf = *reinterpret_cast<const bf16x8*>(KB + krow*128 + ((ks*32 + hi*16) ^ ((krow&7)<<4)));
            s = MFMA32(kf, qa[ks], s);
          }
          if (kvs0 + 31 > qw0){
            #pragma unroll
            for (int r=0; r<16; ++r){
              int kvg = kvs0 + (r&3) + 8*(r>>2) + 4*hi;
              if (kvg > q_l) s[r] += MASKB;
            }
          }
          float mx = s[0];
          #pragma unroll
          for (int r=1; r<16; ++r) mx = fmaxf(mx, s[r]);
          mx = fmaxf(mx, __shfl_xor(mx, 32));
          float mn = fmaxf(m_s, mx);
          float corr = exp2f(m_s - mn);
          float rs = 0.f;
          #pragma unroll
          for (int r=0; r<16; ++r){ float e = exp2f(s[r] - mn); s[r] = e; rs += e; }
          rs += __shfl_xor(rs, 32);
          l_s = l_s*corr + rs;
          m_s = mn;
          acc0 *= corr;
          acc1 *= corr;
          u32 wd0 = cvtpk(s[0], s[1]),   wd1 = cvtpk(s[2], s[3]);
          u32 wd2 = cvtpk(s[4], s[5]),   wd3 = cvtpk(s[6], s[7]);
          u32 wd4 = cvtpk(s[8], s[9]),   wd5 = cvtpk(s[10], s[11]);
          u32 wd6 = cvtpk(s[12], s[13]), wd7 = cvtpk(s[14], s[15]);
          u32 sw0 = __shfl_xor((int)wd0, 32), sw1 = __shfl_xor((int)wd1, 32);
          u32 sw2 = __shfl_xor((int)wd2, 32), sw3 = __shfl_xor((int)wd3, 32);
          u32 sw4 = __shfl_xor((int)wd4, 32), sw5 = __shfl_xor((int)wd5, 32);
          u32 sw6 = __shfl_xor((int)wd6, 32), sw7 = __shfl_xor((int)wd7, 32);
          bf16x8 pf0 = hi ? mkfrag(sw2, sw3, wd2, wd3) : mkfrag(wd0, wd1, sw0, sw1);
          bf16x8 pf1 = hi ? mkfrag(sw6, sw7, wd6, wd7) : mkfrag(wd4, wd5, sw4, sw5);
          {
            int vrow = lo;
            bf16x8 v0 = *reinterpret_cast<const bf16x8*>(VB + vrow*128 + ((t2*64 +      hi*16) ^ ((vrow&7)<<4)));
            bf16x8 v1 = *reinterpret_cast<const bf16x8*>(VB + vrow*128 + ((t2*64 + 32 + hi*16) ^ ((vrow&7)<<4)));
            acc0 = MFMA32(v0, pf0, acc0);
            acc0 = MFMA32(v1, pf1, acc0);
          }
          {
            int vrow = 32 + lo;
            bf16x8 v0 = *reinterpret_cast<const bf16x8*>(VB + vrow*128 + ((t2*64 +      hi*16) ^ ((vrow&7)<<4)));
            bf16x8 v1 = *reinterpret_cast<const bf16x8*>(VB + vrow*128 + ((t2*64 + 32 + hi*16) ^ ((vrow&7)<<4)));
            acc1 = MFMA32(v0, pf0, acc1);
            acc1 = MFMA32(v1, pf1, acc1);
          }
        }
      }
    }
    __syncthreads();
    cur ^= 1;
  }
  #undef STAGE

  char* T = lds + w*4096;        // per-wave [32 q][128B], XOR-swizzled
  float inv = 1.0f / l_s;
  #pragma unroll
  for (int i=0; i<8; ++i){
    int d = (2*i & 3) + 8*(2*i >> 2) + 4*hi;
    u32 wv0 = cvtpk(acc0[2*i]*inv, acc0[2*i+1]*inv);
    *reinterpret_cast<u32*>(T + lo*128 + ((d*2) ^ ((lo&7)<<4))) = wv0;
    u32 wv1 = cvtpk(acc1[2*i]*inv, acc1[2*i+1]*inv);
    *reinterpret_cast<u32*>(T + lo*128 + (((d+32)*2) ^ ((lo&7)<<4))) = wv1;
  }
  __syncthreads();
  const int b = bh >> 4, h = bh & 15;
  #pragma unroll
  for (int i=0; i<4; ++i){
    int q = i*8 + (l>>3), slot = l&7;
    bf16x8 v = *reinterpret_cast<const bf16x8*>(T + q*128 + ((slot*16) ^ ((q&7)<<4)));
    int sq = qb*128 + w*32 + q;
    *reinterpret_cast<bf16x8*>(Ow + ((size_t)(b*2048 + sq))*1024 + h*64 + slot*8) = v;
  }
}

// ---------------- GEMM2: attn @ w_outT^T + bias -> f32 out ----------------
__global__ __launch_bounds__(256,2) void gemm_out_k(const u16* __restrict__ A, const u16* __restrict__ Bt,
                                                    const float* __restrict__ bias_p, float* __restrict__ out){
  __shared__ __align__(16) char lds[32768];
  const f32x4 zero4 = {0.f, 0.f, 0.f, 0.f};
  f32x4 acc[4][4];
  #pragma unroll
  for (int m=0;m<4;++m){
    #pragma unroll
    for (int n=0;n<4;++n) acc[m][n] = zero4;
  }
  int bn = blockIdx.x, bm = blockIdx.y;
  gemm_core(A, Bt, bm, bn, lds, acc);
  int tid = threadIdx.x, w = tid >> 6, l = tid & 63;
  int lrow = l & 15, lg = l >> 4;
  int wm = w >> 1, wn = w & 1;
  #pragma unroll
  for (int n=0;n<4;++n){
    int gcol = bn*128 + wn*64 + n*16 + lrow;
    float bias = bias_p[gcol];
    #pragma unroll
    for (int m=0;m<4;++m){
      #pragma unroll
      for (int r=0;r<4;++r){
        int grow = bm*128 + wm*64 + m*16 + lg*4 + r;
        out[(size_t)grow*1024 + gcol] = acc[m][n][r] + bias;
      }
    }
  }
}

extern "C" void kernel_launch(void* const* d_in, const int* in_sizes, int n_in,
                              void* d_out, int out_size, void* d_ws, size_t ws_size,
                              hipStream_t stream){
  (void)in_sizes; (void)n_in; (void)out_size; (void)ws_size;
  const float* x     = (const float*)d_in[0];
  const float* w_qkv = (const float*)d_in[1];
  const float* w_out = (const float*)d_in[2];
  const float* b_out = (const float*)d_in[3];
  float* out = (float*)d_out;
  char* ws = (char*)d_ws;
  u16* xb    = (u16*)(ws + 0);
  u16* wqkvT = (u16*)(ws + 16777216);
  u16* woutT = (u16*)(ws + 23068672);
  u16* qw    = (u16*)(ws + 25165824);
  u16* kw    = (u16*)(ws + 41943040);
  u16* vtw   = (u16*)(ws + 58720256);
  u16* attn  = (u16*)(ws + 75497472);

  cvt_bf16_k<<<8192, 256, 0, stream>>>(x, xb);
  transpose_cvt_k<<<dim3(48,16), 256, 0, stream>>>(w_qkv, wqkvT, 1024, 3072);
  transpose_cvt_k<<<dim3(16,16), 256, 0, stream>>>(w_out, woutT, 1024, 1024);
  gemm_qkv_k<<<dim3(24,64), 256, 0, stream>>>(xb, wqkvT, qw, kw, vtw);
  attn_k<<<dim3(16,64), 256, 0, stream>>>(qw, kw, vtw, attn);
  gemm_out_k<<<dim3(8,64), 256, 0, stream>>>(attn, woutT, b_out, out);
}

// Round 3
// 239.246 us; speedup vs baseline: 1.5478x; 1.2654x over previous
//
#include <hip/hip_runtime.h>
#include <stdint.h>

typedef unsigned short u16;
typedef uint32_t u32;
typedef __attribute__((ext_vector_type(4))) float f32x4;
typedef __attribute__((ext_vector_type(16))) float f32x16;
typedef __attribute__((ext_vector_type(8))) short bf16x8;
typedef __attribute__((ext_vector_type(4))) u32 u32x4;

#define MFMA16(a,b,c) __builtin_amdgcn_mfma_f32_16x16x32_bf16((a),(b),(c),0,0,0)
#define MFMA32(a,b,c) __builtin_amdgcn_mfma_f32_32x32x16_bf16((a),(b),(c),0,0,0)
#define QSCALE 0.18033688011112042f   /* 0.125 * log2(e) */
#define MASKB  -1803.3688011112042f   /* -10000 * QSCALE */
#define DEFER_THR 8.0f                /* log2-domain defer-max threshold: P <= 2^8 */

__device__ __forceinline__ u16 f2bf(float f){
  union { float f; uint32_t u; } v; v.f = f;
  uint32_t r = v.u + 0x7fffu + ((v.u >> 16) & 1u);
  return (u16)(r >> 16);
}

__device__ __forceinline__ u32 cvtpk(float lo, float hi){
  u32 r;
  asm volatile("v_cvt_pk_bf16_f32 %0, %1, %2" : "=v"(r) : "v"(lo), "v"(hi));
  return r;
}

union U4 { u32x4 u; bf16x8 b; };
__device__ __forceinline__ bf16x8 mkfrag(u32 a, u32 b, u32 c, u32 d){
  U4 x; x.u = (u32x4){a,b,c,d}; return x.b;
}

__device__ __forceinline__ void gload16(const void* g, void* l){
  __builtin_amdgcn_global_load_lds(
      (const __attribute__((address_space(1))) void*)g,
      (__attribute__((address_space(3))) void*)l, 16, 0, 0);
}

// ---------------- pre-pass ----------------
__global__ __launch_bounds__(256) void cvt_bf16_k(const float* __restrict__ in, u16* __restrict__ out){
  int i = blockIdx.x*256 + threadIdx.x;
  float4 v = reinterpret_cast<const float4*>(in)[i];
  ushort4 o;
  o.x = f2bf(v.x); o.y = f2bf(v.y); o.z = f2bf(v.z); o.w = f2bf(v.w);
  reinterpret_cast<ushort4*>(out)[i] = o;
}

// in [R][C] f32 -> out [C][R] bf16
__global__ __launch_bounds__(256) void transpose_cvt_k(const float* __restrict__ in, u16* __restrict__ out,
                                                       int R, int C){
  __shared__ float tile[64][65];
  int c0 = blockIdx.x*64, r0 = blockIdx.y*64;
  int t = threadIdx.x; int cc = t & 63, rr = t >> 6;
  #pragma unroll
  for (int i=0;i<16;++i){ int r = rr + i*4; tile[r][cc] = in[(size_t)(r0+r)*C + c0+cc]; }
  __syncthreads();
  #pragma unroll
  for (int i=0;i<16;++i){ int r = rr + i*4; out[(size_t)(c0+r)*R + r0+cc] = f2bf(tile[cc][r]); }
}

// ---------------- GEMM core: C[128x128] = A[128xK] * Bt[128xK]^T, K=1024 ----------------
__device__ __forceinline__ void gemm_core(const u16* __restrict__ A, const u16* __restrict__ Bt,
                                          int bm, int bn, char* lds, f32x4 (&acc)[4][4]){
  const int K = 1024;
  int tid = threadIdx.x, w = tid >> 6, l = tid & 63;
  int lrow = l & 15, lg = l >> 4;
  int wm = w >> 1, wn = w & 1;
  const u16* aSrc = A + (size_t)(bm*128 + w*32 + (l>>3))*K + (((l&7)^(l>>3))<<3);
  const u16* bSrc = Bt + (size_t)(bn*128 + w*32 + (l>>3))*K + (((l&7)^(l>>3))<<3);
  char* aDst = lds + w*4096;
  char* bDst = lds + 16384 + w*4096;
  for (int kk = 0; kk < 16; ++kk){
    __syncthreads();
    #pragma unroll
    for (int i=0;i<4;++i) gload16(aSrc + (size_t)i*8*K + kk*64, aDst + i*1024);
    #pragma unroll
    for (int i=0;i<4;++i) gload16(bSrc + (size_t)i*8*K + kk*64, bDst + i*1024);
    __syncthreads();
    #pragma unroll
    for (int ks=0; ks<2; ++ks){
      bf16x8 af[4], bfv[4];
      #pragma unroll
      for (int m=0;m<4;++m){
        int row = wm*64 + m*16 + lrow;
        af[m] = *reinterpret_cast<const bf16x8*>(lds + row*128 + (((ks*4+lg)^(row&7))<<4));
      }
      #pragma unroll
      for (int n=0;n<4;++n){
        int row = wn*64 + n*16 + lrow;
        bfv[n] = *reinterpret_cast<const bf16x8*>(lds + 16384 + row*128 + (((ks*4+lg)^(row&7))<<4));
      }
      #pragma unroll
      for (int m=0;m<4;++m){
        #pragma unroll
        for (int n=0;n<4;++n)
          acc[m][n] = MFMA16(af[m], bfv[n], acc[m][n]);
      }
    }
  }
}

// ---------------- GEMM1: x_bf16 @ w_qkvT^T -> scatter q,k,vT ----------------
__global__ __launch_bounds__(256,2) void gemm_qkv_k(const u16* __restrict__ A, const u16* __restrict__ Bt,
                                                    u16* __restrict__ qw, u16* __restrict__ kw,
                                                    u16* __restrict__ vtw){
  __shared__ __align__(16) char lds[32768];
  const f32x4 zero4 = {0.f, 0.f, 0.f, 0.f};
  f32x4 acc[4][4];
  #pragma unroll
  for (int m=0;m<4;++m){
    #pragma unroll
    for (int n=0;n<4;++n) acc[m][n] = zero4;
  }
  int bn = blockIdx.x, bm = blockIdx.y;
  gemm_core(A, Bt, bm, bn, lds, acc);
  int tid = threadIdx.x, w = tid >> 6, l = tid & 63;
  int lrow = l & 15, lg = l >> 4;
  int wm = w >> 1, wn = w & 1;
  #pragma unroll
  for (int n=0;n<4;++n){
    int gcol = bn*128 + wn*64 + n*16 + lrow;        // 0..3071
    int which = gcol >> 10;
    int inner = gcol & 1023;
    int h = inner >> 6, d = inner & 63;
    #pragma unroll
    for (int m=0;m<4;++m){
      #pragma unroll
      for (int r=0;r<4;++r){
        int grow = bm*128 + wm*64 + m*16 + lg*4 + r; // b*S + s
        int b = grow >> 11, sq = grow & 2047;
        float v = acc[m][n][r];
        if (which == 0)
          qw[((size_t)((b*16 + h)*2048 + sq))*64 + d] = f2bf(v * QSCALE);
        else if (which == 1)
          kw[((size_t)((b*16 + h)*2048 + sq))*64 + d] = f2bf(v);
        else
          vtw[((size_t)((b*16 + h)*64 + d))*2048 + sq] = f2bf(v);
      }
    }
  }
}

// ---------------- flash attention v3: grid (bh, qb), tree reduce, defer-max ----------------
__global__ __launch_bounds__(256) void attn_k(const u16* __restrict__ Qw, const u16* __restrict__ Kw,
                                              const u16* __restrict__ VTw, u16* __restrict__ Ow){
  __shared__ __align__(16) char lds[32768];   // 2 x (K 8KB + V 8KB)
  const int bh = blockIdx.x;                  // 64: balanced + same-XCD per bh
  const int qb = blockIdx.y;                  // 16 q-blocks of 128 rows
  const int tid = threadIdx.x, w = tid >> 6, l = tid & 63;
  const int lo = l & 31, hi = l >> 5;
  const size_t base = (size_t)bh * (2048*64);
  const int qw0 = qb*128 + w*32;
  const int q_l = qw0 + lo;

  bf16x8 qa[4];
  {
    const u16* qsrc = Qw + base + (size_t)q_l*64 + hi*8;
    #pragma unroll
    for (int ks=0; ks<4; ++ks) qa[ks] = *reinterpret_cast<const bf16x8*>(qsrc + ks*16);
  }

  const int srow = tid >> 3;                 // 0..31
  const int scs  = (tid & 7) ^ (srow & 7);   // pre-swizzled 16B slot
  const u16* kS = Kw  + base + (size_t)srow*64   + scs*8;
  const u16* vS = VTw + base + (size_t)srow*2048 + scs*8;

  f32x16 acc0 = {0,0,0,0,0,0,0,0,0,0,0,0,0,0,0,0};
  f32x16 acc1 = {0,0,0,0,0,0,0,0,0,0,0,0,0,0,0,0};
  float m_s = -1e30f, l_s = 0.f;

  const int nt = qb*2 + 2;

  #define STAGE(buf, t) do { \
    int kv0_ = (t)*64; \
    gload16(kS + (size_t)kv0_*64,        lds + (buf)*16384 +     0 + w*1024); \
    gload16(kS + (size_t)(kv0_+32)*64,   lds + (buf)*16384 +  4096 + w*1024); \
    gload16(vS + kv0_,                   lds + (buf)*16384 +  8192 + w*1024); \
    gload16(vS + kv0_ + (size_t)32*2048, lds + (buf)*16384 + 12288 + w*1024); \
  } while(0)

  STAGE(0, 0);
  __syncthreads();

  int cur = 0;
  for (int t = 0; t < nt; ++t){
    if (t+1 < nt){
      if (cur) STAGE(0, t+1); else STAGE(1, t+1);
    }
    const int kv0 = t*64;
    if (kv0 < qw0 + 32){
      const char* KB = lds + cur*16384;
      const char* VB = KB + 8192;
      #pragma unroll
      for (int t2=0; t2<2; ++t2){
        const int kvs0 = kv0 + t2*32;
        if (kvs0 < qw0 + 32){
          f32x16 s = {0,0,0,0,0,0,0,0,0,0,0,0,0,0,0,0};
          #pragma unroll
          for (int ks=0; ks<4; ++ks){
            int krow = t2*32 + lo;
            bf16x8 kf = *reinterpret_cast<const bf16x8*>(KB + krow*128 + ((ks*32 + hi*16) ^ ((krow&7)<<4)));
            s = MFMA32(kf, qa[ks], s);
          }
          if (kvs0 + 31 > qw0){
            #pragma unroll
            for (int r=0; r<16; ++r){
              int kvg = kvs0 + (r&3) + 8*(r>>2) + 4*hi;
              if (kvg > q_l) s[r] += MASKB;
            }
          }
          // tree max (depth 4) + cross-half
          float t0 = fmaxf(s[0], s[1]),  t1 = fmaxf(s[2], s[3]);
          float t2m= fmaxf(s[4], s[5]),  t3 = fmaxf(s[6], s[7]);
          float t4 = fmaxf(s[8], s[9]),  t5 = fmaxf(s[10], s[11]);
          float t6 = fmaxf(s[12], s[13]),t7 = fmaxf(s[14], s[15]);
          float u0 = fmaxf(t0, t1), u1 = fmaxf(t2m, t3), u2 = fmaxf(t4, t5), u3 = fmaxf(t6, t7);
          float mx = fmaxf(fmaxf(u0, u1), fmaxf(u2, u3));
          mx = fmaxf(mx, __shfl_xor(mx, 32));
          // defer-max: skip rescale when max growth small
          if (!__all(mx - m_s <= DEFER_THR)){
            float mn = fmaxf(m_s, mx);
            float corr = exp2f(m_s - mn);
            m_s = mn;
            l_s *= corr;
            acc0 *= corr;
            acc1 *= corr;
          }
          // exponentials + tree sum
          #pragma unroll
          for (int r=0; r<16; ++r) s[r] = exp2f(s[r] - m_s);
          float a0 = (s[0]+s[1]) + (s[2]+s[3]);
          float a1 = (s[4]+s[5]) + (s[6]+s[7]);
          float a2 = (s[8]+s[9]) + (s[10]+s[11]);
          float a3 = (s[12]+s[13]) + (s[14]+s[15]);
          float rs = (a0+a1) + (a2+a3);
          rs += __shfl_xor(rs, 32);
          l_s += rs;
          u32 wd0 = cvtpk(s[0], s[1]),   wd1 = cvtpk(s[2], s[3]);
          u32 wd2 = cvtpk(s[4], s[5]),   wd3 = cvtpk(s[6], s[7]);
          u32 wd4 = cvtpk(s[8], s[9]),   wd5 = cvtpk(s[10], s[11]);
          u32 wd6 = cvtpk(s[12], s[13]), wd7 = cvtpk(s[14], s[15]);
          u32 sw0 = __shfl_xor((int)wd0, 32), sw1 = __shfl_xor((int)wd1, 32);
          u32 sw2 = __shfl_xor((int)wd2, 32), sw3 = __shfl_xor((int)wd3, 32);
          u32 sw4 = __shfl_xor((int)wd4, 32), sw5 = __shfl_xor((int)wd5, 32);
          u32 sw6 = __shfl_xor((int)wd6, 32), sw7 = __shfl_xor((int)wd7, 32);
          bf16x8 pf0 = hi ? mkfrag(sw2, sw3, wd2, wd3) : mkfrag(wd0, wd1, sw0, sw1);
          bf16x8 pf1 = hi ? mkfrag(sw6, sw7, wd6, wd7) : mkfrag(wd4, wd5, sw4, sw5);
          {
            int vrow = lo;
            bf16x8 v0 = *reinterpret_cast<const bf16x8*>(VB + vrow*128 + ((t2*64 +      hi*16) ^ ((vrow&7)<<4)));
            bf16x8 v1 = *reinterpret_cast<const bf16x8*>(VB + vrow*128 + ((t2*64 + 32 + hi*16) ^ ((vrow&7)<<4)));
            acc0 = MFMA32(v0, pf0, acc0);
            acc0 = MFMA32(v1, pf1, acc0);
          }
          {
            int vrow = 32 + lo;
            bf16x8 v0 = *reinterpret_cast<const bf16x8*>(VB + vrow*128 + ((t2*64 +      hi*16) ^ ((vrow&7)<<4)));
            bf16x8 v1 = *reinterpret_cast<const bf16x8*>(VB + vrow*128 + ((t2*64 + 32 + hi*16) ^ ((vrow&7)<<4)));
            acc1 = MFMA32(v0, pf0, acc1);
            acc1 = MFMA32(v1, pf1, acc1);
          }
        }
      }
    }
    __syncthreads();
    cur ^= 1;
  }
  #undef STAGE

  char* T = lds + w*4096;        // per-wave [32 q][128B], XOR-swizzled
  float inv = 1.0f / l_s;
  #pragma unroll
  for (int i=0; i<8; ++i){
    int d = (2*i & 3) + 8*(2*i >> 2) + 4*hi;
    u32 wv0 = cvtpk(acc0[2*i]*inv, acc0[2*i+1]*inv);
    *reinterpret_cast<u32*>(T + lo*128 + ((d*2) ^ ((lo&7)<<4))) = wv0;
    u32 wv1 = cvtpk(acc1[2*i]*inv, acc1[2*i+1]*inv);
    *reinterpret_cast<u32*>(T + lo*128 + (((d+32)*2) ^ ((lo&7)<<4))) = wv1;
  }
  __syncthreads();
  const int b = bh >> 4, h = bh & 15;
  #pragma unroll
  for (int i=0; i<4; ++i){
    int q = i*8 + (l>>3), slot = l&7;
    bf16x8 v = *reinterpret_cast<const bf16x8*>(T + q*128 + ((slot*16) ^ ((q&7)<<4)));
    int sq = qb*128 + w*32 + q;
    *reinterpret_cast<bf16x8*>(Ow + ((size_t)(b*2048 + sq))*1024 + h*64 + slot*8) = v;
  }
}

// ---------------- GEMM2: attn @ w_outT^T + bias -> f32 out ----------------
__global__ __launch_bounds__(256,2) void gemm_out_k(const u16* __restrict__ A, const u16* __restrict__ Bt,
                                                    const float* __restrict__ bias_p, float* __restrict__ out){
  __shared__ __align__(16) char lds[32768];
  const f32x4 zero4 = {0.f, 0.f, 0.f, 0.f};
  f32x4 acc[4][4];
  #pragma unroll
  for (int m=0;m<4;++m){
    #pragma unroll
    for (int n=0;n<4;++n) acc[m][n] = zero4;
  }
  int bn = blockIdx.x, bm = blockIdx.y;
  gemm_core(A, Bt, bm, bn, lds, acc);
  int tid = threadIdx.x, w = tid >> 6, l = tid & 63;
  int lrow = l & 15, lg = l >> 4;
  int wm = w >> 1, wn = w & 1;
  #pragma unroll
  for (int n=0;n<4;++n){
    int gcol = bn*128 + wn*64 + n*16 + lrow;
    float bias = bias_p[gcol];
    #pragma unroll
    for (int m=0;m<4;++m){
      #pragma unroll
      for (int r=0;r<4;++r){
        int grow = bm*128 + wm*64 + m*16 + lg*4 + r;
        out[(size_t)grow*1024 + gcol] = acc[m][n][r] + bias;
      }
    }
  }
}

extern "C" void kernel_launch(void* const* d_in, const int* in_sizes, int n_in,
                              void* d_out, int out_size, void* d_ws, size_t ws_size,
                              hipStream_t stream){
  (void)in_sizes; (void)n_in; (void)out_size; (void)ws_size;
  const float* x     = (const float*)d_in[0];
  const float* w_qkv = (const float*)d_in[1];
  const float* w_out = (const float*)d_in[2];
  const float* b_out = (const float*)d_in[3];
  float* out = (float*)d_out;
  char* ws = (char*)d_ws;
  u16* xb    = (u16*)(ws + 0);
  u16* wqkvT = (u16*)(ws + 16777216);
  u16* woutT = (u16*)(ws + 23068672);
  u16* qw    = (u16*)(ws + 25165824);
  u16* kw    = (u16*)(ws + 41943040);
  u16* vtw   = (u16*)(ws + 58720256);
  u16* attn  = (u16*)(ws + 75497472);

  cvt_bf16_k<<<8192, 256, 0, stream>>>(x, xb);
  transpose_cvt_k<<<dim3(48,16), 256, 0, stream>>>(w_qkv, wqkvT, 1024, 3072);
  transpose_cvt_k<<<dim3(16,16), 256, 0, stream>>>(w_out, woutT, 1024, 1024);
  gemm_qkv_k<<<dim3(24,64), 256, 0, stream>>>(xb, wqkvT, qw, kw, vtw);
  attn_k<<<dim3(64,16), 256, 0, stream>>>(qw, kw, vtw, attn);
  gemm_out_k<<<dim3(8,64), 256, 0, stream>>>(attn, woutT, b_out, out);
}

// Round 4
// 214.193 us; speedup vs baseline: 1.7288x; 1.1170x over previous
//
#include <hip/hip_runtime.h>
#include <stdint.h>

typedef unsigned short u16;
typedef uint32_t u32;
typedef __attribute__((ext_vector_type(4))) float f32x4;
typedef __attribute__((ext_vector_type(16))) float f32x16;
typedef __attribute__((ext_vector_type(8))) short bf16x8;
typedef __attribute__((ext_vector_type(4))) u32 u32x4;

#define MFMA16(a,b,c) __builtin_amdgcn_mfma_f32_16x16x32_bf16((a),(b),(c),0,0,0)
#define MFMA32(a,b,c) __builtin_amdgcn_mfma_f32_32x32x16_bf16((a),(b),(c),0,0,0)
#define QSCALE 0.18033688011112042f   /* 0.125 * log2(e) */
#define MASKB  -1803.3688011112042f   /* -10000 * QSCALE */
#define DEFER_THR 8.0f                /* log2-domain defer-max threshold: P <= 2^8 */

__device__ __forceinline__ u16 f2bf(float f){
  union { float f; uint32_t u; } v; v.f = f;
  uint32_t r = v.u + 0x7fffu + ((v.u >> 16) & 1u);
  return (u16)(r >> 16);
}

__device__ __forceinline__ u32 cvtpk(float lo, float hi){
  u32 r;
  asm volatile("v_cvt_pk_bf16_f32 %0, %1, %2" : "=v"(r) : "v"(lo), "v"(hi));
  return r;
}

// cross-half exchange: after plswap(a,b):
//   a = {a[0:31], b[0:31]->hi}, b = {a[32:63]->lo, b[32:63]}
__device__ __forceinline__ void plswap(u32 &a, u32 &b){
  auto r = __builtin_amdgcn_permlane32_swap(a, b, false, false);
  union { decltype(r) v; u32 w[2]; } u; u.v = r;
  a = u.w[0]; b = u.w[1];
}

union U4 { u32x4 u; bf16x8 b; };
__device__ __forceinline__ bf16x8 mkfrag(u32 a, u32 b, u32 c, u32 d){
  U4 x; x.u = (u32x4){a,b,c,d}; return x.b;
}

__device__ __forceinline__ void gload16(const void* g, void* l){
  __builtin_amdgcn_global_load_lds(
      (const __attribute__((address_space(1))) void*)g,
      (__attribute__((address_space(3))) void*)l, 16, 0, 0);
}

// ---------------- pre-pass ----------------
__global__ __launch_bounds__(256) void cvt_bf16_k(const float* __restrict__ in, u16* __restrict__ out){
  int i = blockIdx.x*256 + threadIdx.x;
  float4 v = reinterpret_cast<const float4*>(in)[i];
  ushort4 o;
  o.x = f2bf(v.x); o.y = f2bf(v.y); o.z = f2bf(v.z); o.w = f2bf(v.w);
  reinterpret_cast<ushort4*>(out)[i] = o;
}

// in [R][C] f32 -> out [C][R] bf16
__global__ __launch_bounds__(256) void transpose_cvt_k(const float* __restrict__ in, u16* __restrict__ out,
                                                       int R, int C){
  __shared__ float tile[64][65];
  int c0 = blockIdx.x*64, r0 = blockIdx.y*64;
  int t = threadIdx.x; int cc = t & 63, rr = t >> 6;
  #pragma unroll
  for (int i=0;i<16;++i){ int r = rr + i*4; tile[r][cc] = in[(size_t)(r0+r)*C + c0+cc]; }
  __syncthreads();
  #pragma unroll
  for (int i=0;i<16;++i){ int r = rr + i*4; out[(size_t)(c0+r)*R + r0+cc] = f2bf(tile[cc][r]); }
}

// ---------------- GEMM core: C[128x128] = A[128xK] * Bt[128xK]^T, K=1024 ----------------
__device__ __forceinline__ void gemm_core(const u16* __restrict__ A, const u16* __restrict__ Bt,
                                          int bm, int bn, char* lds, f32x4 (&acc)[4][4]){
  const int K = 1024;
  int tid = threadIdx.x, w = tid >> 6, l = tid & 63;
  int lrow = l & 15, lg = l >> 4;
  int wm = w >> 1, wn = w & 1;
  const u16* aSrc = A + (size_t)(bm*128 + w*32 + (l>>3))*K + (((l&7)^(l>>3))<<3);
  const u16* bSrc = Bt + (size_t)(bn*128 + w*32 + (l>>3))*K + (((l&7)^(l>>3))<<3);
  char* aDst = lds + w*4096;
  char* bDst = lds + 16384 + w*4096;
  for (int kk = 0; kk < 16; ++kk){
    __syncthreads();
    #pragma unroll
    for (int i=0;i<4;++i) gload16(aSrc + (size_t)i*8*K + kk*64, aDst + i*1024);
    #pragma unroll
    for (int i=0;i<4;++i) gload16(bSrc + (size_t)i*8*K + kk*64, bDst + i*1024);
    __syncthreads();
    #pragma unroll
    for (int ks=0; ks<2; ++ks){
      bf16x8 af[4], bfv[4];
      #pragma unroll
      for (int m=0;m<4;++m){
        int row = wm*64 + m*16 + lrow;
        af[m] = *reinterpret_cast<const bf16x8*>(lds + row*128 + (((ks*4+lg)^(row&7))<<4));
      }
      #pragma unroll
      for (int n=0;n<4;++n){
        int row = wn*64 + n*16 + lrow;
        bfv[n] = *reinterpret_cast<const bf16x8*>(lds + 16384 + row*128 + (((ks*4+lg)^(row&7))<<4));
      }
      #pragma unroll
      for (int m=0;m<4;++m){
        #pragma unroll
        for (int n=0;n<4;++n)
          acc[m][n] = MFMA16(af[m], bfv[n], acc[m][n]);
      }
    }
  }
}

// ---------------- GEMM1: x_bf16 @ w_qkvT^T -> scatter q,k,vT ----------------
__global__ __launch_bounds__(256,2) void gemm_qkv_k(const u16* __restrict__ A, const u16* __restrict__ Bt,
                                                    u16* __restrict__ qw, u16* __restrict__ kw,
                                                    u16* __restrict__ vtw){
  __shared__ __align__(16) char lds[32768];
  const f32x4 zero4 = {0.f, 0.f, 0.f, 0.f};
  f32x4 acc[4][4];
  #pragma unroll
  for (int m=0;m<4;++m){
    #pragma unroll
    for (int n=0;n<4;++n) acc[m][n] = zero4;
  }
  int bn = blockIdx.x, bm = blockIdx.y;
  gemm_core(A, Bt, bm, bn, lds, acc);
  int tid = threadIdx.x, w = tid >> 6, l = tid & 63;
  int lrow = l & 15, lg = l >> 4;
  int wm = w >> 1, wn = w & 1;
  #pragma unroll
  for (int n=0;n<4;++n){
    int gcol = bn*128 + wn*64 + n*16 + lrow;        // 0..3071
    int which = gcol >> 10;
    int inner = gcol & 1023;
    int h = inner >> 6, d = inner & 63;
    #pragma unroll
    for (int m=0;m<4;++m){
      #pragma unroll
      for (int r=0;r<4;++r){
        int grow = bm*128 + wm*64 + m*16 + lg*4 + r; // b*S + s
        int b = grow >> 11, sq = grow & 2047;
        float v = acc[m][n][r];
        if (which == 0)
          qw[((size_t)((b*16 + h)*2048 + sq))*64 + d] = f2bf(v * QSCALE);
        else if (which == 1)
          kw[((size_t)((b*16 + h)*2048 + sq))*64 + d] = f2bf(v);
        else
          vtw[((size_t)((b*16 + h)*64 + d))*2048 + sq] = f2bf(v);
      }
    }
  }
}

// ---------------- flash attention v4: fused-tile fast path, permlane, balanced grid ----------------
__global__ __launch_bounds__(256) void attn_k(const u16* __restrict__ Qw, const u16* __restrict__ Kw,
                                              const u16* __restrict__ VTw, u16* __restrict__ Ow){
  __shared__ __align__(16) char lds[32768];   // 2 x (K 8KB + V 8KB)
  const int bh = blockIdx.x;                  // 64: balanced + same-XCD per bh
  // balanced qb permutation: per-CU resident set {y, y+4, y+8, y+12} maps to qb summing to 30
  const int y = blockIdx.y, yk = y >> 2, ya = y & 3;
  const int qb = (yk == 0) ? (15 - ya) : (yk == 1) ? (8 + ya) : (yk == 2) ? (4 + ya) : (3 - ya);
  const int tid = threadIdx.x, w = tid >> 6, l = tid & 63;
  const int lo = l & 31, hi = l >> 5;
  const size_t base = (size_t)bh * (2048*64);
  const int qw0 = qb*128 + w*32;
  const int q_l = qw0 + lo;

  bf16x8 qa[4];
  {
    const u16* qsrc = Qw + base + (size_t)q_l*64 + hi*8;
    #pragma unroll
    for (int ks=0; ks<4; ++ks) qa[ks] = *reinterpret_cast<const bf16x8*>(qsrc + ks*16);
  }

  const int srow = tid >> 3;                 // 0..31
  const int scs  = (tid & 7) ^ (srow & 7);   // pre-swizzled 16B slot
  const u16* kS = Kw  + base + (size_t)srow*64   + scs*8;
  const u16* vS = VTw + base + (size_t)srow*2048 + scs*8;

  f32x16 acc0 = {0,0,0,0,0,0,0,0,0,0,0,0,0,0,0,0};
  f32x16 acc1 = {0,0,0,0,0,0,0,0,0,0,0,0,0,0,0,0};
  float m_s = -1e30f, l_s = 0.f;

  const int nt = qb*2 + 2;

  #define STAGE(buf, t) do { \
    int kv0_ = (t)*64; \
    gload16(kS + (size_t)kv0_*64,        lds + (buf)*16384 +     0 + w*1024); \
    gload16(kS + (size_t)(kv0_+32)*64,   lds + (buf)*16384 +  4096 + w*1024); \
    gload16(vS + kv0_,                   lds + (buf)*16384 +  8192 + w*1024); \
    gload16(vS + kv0_ + (size_t)32*2048, lds + (buf)*16384 + 12288 + w*1024); \
  } while(0)

  STAGE(0, 0);
  __syncthreads();

  int cur = 0;
  for (int t = 0; t < nt; ++t){
    if (t+1 < nt){
      if (cur) STAGE(0, t+1); else STAGE(1, t+1);
    }
    const int kv0 = t*64;
    const char* KB = lds + cur*16384;
    const char* VB = KB + 8192;
    if (kv0 + 63 <= qw0){
      // ---------- FAST path: full 64-kv tile, no mask, merged softmax ----------
      f32x16 s0 = {0,0,0,0,0,0,0,0,0,0,0,0,0,0,0,0};
      f32x16 s1 = {0,0,0,0,0,0,0,0,0,0,0,0,0,0,0,0};
      __builtin_amdgcn_s_setprio(1);
      #pragma unroll
      for (int ks=0; ks<4; ++ks){
        int kr0 = lo, kr1 = 32 + lo;
        bf16x8 kf0 = *reinterpret_cast<const bf16x8*>(KB + kr0*128 + ((ks*32 + hi*16) ^ ((kr0&7)<<4)));
        bf16x8 kf1 = *reinterpret_cast<const bf16x8*>(KB + kr1*128 + ((ks*32 + hi*16) ^ ((kr1&7)<<4)));
        s0 = MFMA32(kf0, qa[ks], s0);
        s1 = MFMA32(kf1, qa[ks], s1);
      }
      __builtin_amdgcn_s_setprio(0);
      // merged tree max over 32
      float m0a = fmaxf(fmaxf(fmaxf(s0[0],s0[1]), fmaxf(s0[2],s0[3])), fmaxf(fmaxf(s0[4],s0[5]), fmaxf(s0[6],s0[7])));
      float m0b = fmaxf(fmaxf(fmaxf(s0[8],s0[9]), fmaxf(s0[10],s0[11])), fmaxf(fmaxf(s0[12],s0[13]), fmaxf(s0[14],s0[15])));
      float m1a = fmaxf(fmaxf(fmaxf(s1[0],s1[1]), fmaxf(s1[2],s1[3])), fmaxf(fmaxf(s1[4],s1[5]), fmaxf(s1[6],s1[7])));
      float m1b = fmaxf(fmaxf(fmaxf(s1[8],s1[9]), fmaxf(s1[10],s1[11])), fmaxf(fmaxf(s1[12],s1[13]), fmaxf(s1[14],s1[15])));
      float mx = fmaxf(fmaxf(m0a, m0b), fmaxf(m1a, m1b));
      mx = fmaxf(mx, __shfl_xor(mx, 32));
      if (!__all(mx - m_s <= DEFER_THR)){
        float mn = fmaxf(m_s, mx);
        float corr = exp2f(m_s - mn);
        m_s = mn;
        l_s *= corr;
        acc0 *= corr;
        acc1 *= corr;
      }
      #pragma unroll
      for (int r=0; r<16; ++r) s0[r] = exp2f(s0[r] - m_s);
      #pragma unroll
      for (int r=0; r<16; ++r) s1[r] = exp2f(s1[r] - m_s);
      float rsa = ((s0[0]+s0[1])+(s0[2]+s0[3])) + ((s0[4]+s0[5])+(s0[6]+s0[7]));
      float rsb = ((s0[8]+s0[9])+(s0[10]+s0[11])) + ((s0[12]+s0[13])+(s0[14]+s0[15]));
      float rsc = ((s1[0]+s1[1])+(s1[2]+s1[3])) + ((s1[4]+s1[5])+(s1[6]+s1[7]));
      float rsd = ((s1[8]+s1[9])+(s1[10]+s1[11])) + ((s1[12]+s1[13])+(s1[14]+s1[15]));
      float rs = (rsa+rsb) + (rsc+rsd);
      rs += __shfl_xor(rs, 32);
      l_s += rs;
      u32 wd0 = cvtpk(s0[0],s0[1]),   wd1 = cvtpk(s0[2],s0[3]);
      u32 wd2 = cvtpk(s0[4],s0[5]),   wd3 = cvtpk(s0[6],s0[7]);
      u32 wd4 = cvtpk(s0[8],s0[9]),   wd5 = cvtpk(s0[10],s0[11]);
      u32 wd6 = cvtpk(s0[12],s0[13]), wd7 = cvtpk(s0[14],s0[15]);
      u32 we0 = cvtpk(s1[0],s1[1]),   we1 = cvtpk(s1[2],s1[3]);
      u32 we2 = cvtpk(s1[4],s1[5]),   we3 = cvtpk(s1[6],s1[7]);
      u32 we4 = cvtpk(s1[8],s1[9]),   we5 = cvtpk(s1[10],s1[11]);
      u32 we6 = cvtpk(s1[12],s1[13]), we7 = cvtpk(s1[14],s1[15]);
      plswap(wd0, wd2); plswap(wd1, wd3); plswap(wd4, wd6); plswap(wd5, wd7);
      plswap(we0, we2); plswap(we1, we3); plswap(we4, we6); plswap(we5, we7);
      bf16x8 pf0 = mkfrag(wd0, wd1, wd2, wd3);
      bf16x8 pf1 = mkfrag(wd4, wd5, wd6, wd7);
      bf16x8 pf2 = mkfrag(we0, we1, we2, we3);
      bf16x8 pf3 = mkfrag(we4, we5, we6, we7);
      __builtin_amdgcn_s_setprio(1);
      {
        int vrow = lo;
        bf16x8 v0 = *reinterpret_cast<const bf16x8*>(VB + vrow*128 + ((      hi*16) ^ ((vrow&7)<<4)));
        bf16x8 v1 = *reinterpret_cast<const bf16x8*>(VB + vrow*128 + (( 32 + hi*16) ^ ((vrow&7)<<4)));
        bf16x8 v2 = *reinterpret_cast<const bf16x8*>(VB + vrow*128 + (( 64 + hi*16) ^ ((vrow&7)<<4)));
        bf16x8 v3 = *reinterpret_cast<const bf16x8*>(VB + vrow*128 + (( 96 + hi*16) ^ ((vrow&7)<<4)));
        acc0 = MFMA32(v0, pf0, acc0);
        acc0 = MFMA32(v1, pf1, acc0);
        acc0 = MFMA32(v2, pf2, acc0);
        acc0 = MFMA32(v3, pf3, acc0);
      }
      {
        int vrow = 32 + lo;
        bf16x8 v0 = *reinterpret_cast<const bf16x8*>(VB + vrow*128 + ((      hi*16) ^ ((vrow&7)<<4)));
        bf16x8 v1 = *reinterpret_cast<const bf16x8*>(VB + vrow*128 + (( 32 + hi*16) ^ ((vrow&7)<<4)));
        bf16x8 v2 = *reinterpret_cast<const bf16x8*>(VB + vrow*128 + (( 64 + hi*16) ^ ((vrow&7)<<4)));
        bf16x8 v3 = *reinterpret_cast<const bf16x8*>(VB + vrow*128 + (( 96 + hi*16) ^ ((vrow&7)<<4)));
        acc1 = MFMA32(v0, pf0, acc1);
        acc1 = MFMA32(v1, pf1, acc1);
        acc1 = MFMA32(v2, pf2, acc1);
        acc1 = MFMA32(v3, pf3, acc1);
      }
      __builtin_amdgcn_s_setprio(0);
    } else if (kv0 < qw0 + 32){
      // ---------- SLOW path: diagonal tile, per-subtile with mask ----------
      #pragma unroll
      for (int t2=0; t2<2; ++t2){
        const int kvs0 = kv0 + t2*32;
        if (kvs0 < qw0 + 32){
          f32x16 s = {0,0,0,0,0,0,0,0,0,0,0,0,0,0,0,0};
          __builtin_amdgcn_s_setprio(1);
          #pragma unroll
          for (int ks=0; ks<4; ++ks){
            int krow = t2*32 + lo;
            bf16x8 kf = *reinterpret_cast<const bf16x8*>(KB + krow*128 + ((ks*32 + hi*16) ^ ((krow&7)<<4)));
            s = MFMA32(kf, qa[ks], s);
          }
          __builtin_amdgcn_s_setprio(0);
          if (kvs0 + 31 > qw0){
            #pragma unroll
            for (int r=0; r<16; ++r){
              int kvg = kvs0 + (r&3) + 8*(r>>2) + 4*hi;
              if (kvg > q_l) s[r] += MASKB;
            }
          }
          float t0 = fmaxf(s[0], s[1]),  t1 = fmaxf(s[2], s[3]);
          float t2m= fmaxf(s[4], s[5]),  t3 = fmaxf(s[6], s[7]);
          float t4 = fmaxf(s[8], s[9]),  t5 = fmaxf(s[10], s[11]);
          float t6 = fmaxf(s[12], s[13]),t7 = fmaxf(s[14], s[15]);
          float u0 = fmaxf(t0, t1), u1 = fmaxf(t2m, t3), u2 = fmaxf(t4, t5), u3 = fmaxf(t6, t7);
          float mx = fmaxf(fmaxf(u0, u1), fmaxf(u2, u3));
          mx = fmaxf(mx, __shfl_xor(mx, 32));
          if (!__all(mx - m_s <= DEFER_THR)){
            float mn = fmaxf(m_s, mx);
            float corr = exp2f(m_s - mn);
            m_s = mn;
            l_s *= corr;
            acc0 *= corr;
            acc1 *= corr;
          }
          #pragma unroll
          for (int r=0; r<16; ++r) s[r] = exp2f(s[r] - m_s);
          float a0 = (s[0]+s[1]) + (s[2]+s[3]);
          float a1 = (s[4]+s[5]) + (s[6]+s[7]);
          float a2 = (s[8]+s[9]) + (s[10]+s[11]);
          float a3 = (s[12]+s[13]) + (s[14]+s[15]);
          float rs = (a0+a1) + (a2+a3);
          rs += __shfl_xor(rs, 32);
          l_s += rs;
          u32 wd0 = cvtpk(s[0], s[1]),   wd1 = cvtpk(s[2], s[3]);
          u32 wd2 = cvtpk(s[4], s[5]),   wd3 = cvtpk(s[6], s[7]);
          u32 wd4 = cvtpk(s[8], s[9]),   wd5 = cvtpk(s[10], s[11]);
          u32 wd6 = cvtpk(s[12], s[13]), wd7 = cvtpk(s[14], s[15]);
          plswap(wd0, wd2); plswap(wd1, wd3);
          plswap(wd4, wd6); plswap(wd5, wd7);
          bf16x8 pf0 = mkfrag(wd0, wd1, wd2, wd3);
          bf16x8 pf1 = mkfrag(wd4, wd5, wd6, wd7);
          __builtin_amdgcn_s_setprio(1);
          {
            int vrow = lo;
            bf16x8 v0 = *reinterpret_cast<const bf16x8*>(VB + vrow*128 + ((t2*64 +      hi*16) ^ ((vrow&7)<<4)));
            bf16x8 v1 = *reinterpret_cast<const bf16x8*>(VB + vrow*128 + ((t2*64 + 32 + hi*16) ^ ((vrow&7)<<4)));
            acc0 = MFMA32(v0, pf0, acc0);
            acc0 = MFMA32(v1, pf1, acc0);
          }
          {
            int vrow = 32 + lo;
            bf16x8 v0 = *reinterpret_cast<const bf16x8*>(VB + vrow*128 + ((t2*64 +      hi*16) ^ ((vrow&7)<<4)));
            bf16x8 v1 = *reinterpret_cast<const bf16x8*>(VB + vrow*128 + ((t2*64 + 32 + hi*16) ^ ((vrow&7)<<4)));
            acc1 = MFMA32(v0, pf0, acc1);
            acc1 = MFMA32(v1, pf1, acc1);
          }
          __builtin_amdgcn_s_setprio(0);
        }
      }
    }
    __syncthreads();
    cur ^= 1;
  }
  #undef STAGE

  char* T = lds + w*4096;        // per-wave [32 q][128B], XOR-swizzled
  float inv = 1.0f / l_s;
  #pragma unroll
  for (int i=0; i<8; ++i){
    int d = (2*i & 3) + 8*(2*i >> 2) + 4*hi;
    u32 wv0 = cvtpk(acc0[2*i]*inv, acc0[2*i+1]*inv);
    *reinterpret_cast<u32*>(T + lo*128 + ((d*2) ^ ((lo&7)<<4))) = wv0;
    u32 wv1 = cvtpk(acc1[2*i]*inv, acc1[2*i+1]*inv);
    *reinterpret_cast<u32*>(T + lo*128 + (((d+32)*2) ^ ((lo&7)<<4))) = wv1;
  }
  __syncthreads();
  const int b = bh >> 4, h = bh & 15;
  #pragma unroll
  for (int i=0; i<4; ++i){
    int q = i*8 + (l>>3), slot = l&7;
    bf16x8 v = *reinterpret_cast<const bf16x8*>(T + q*128 + ((slot*16) ^ ((q&7)<<4)));
    int sq = qb*128 + w*32 + q;
    *reinterpret_cast<bf16x8*>(Ow + ((size_t)(b*2048 + sq))*1024 + h*64 + slot*8) = v;
  }
}

// ---------------- GEMM2: attn @ w_outT^T + bias -> f32 out ----------------
__global__ __launch_bounds__(256,2) void gemm_out_k(const u16* __restrict__ A, const u16* __restrict__ Bt,
                                                    const float* __restrict__ bias_p, float* __restrict__ out){
  __shared__ __align__(16) char lds[32768];
  const f32x4 zero4 = {0.f, 0.f, 0.f, 0.f};
  f32x4 acc[4][4];
  #pragma unroll
  for (int m=0;m<4;++m){
    #pragma unroll
    for (int n=0;n<4;++n) acc[m][n] = zero4;
  }
  int bn = blockIdx.x, bm = blockIdx.y;
  gemm_core(A, Bt, bm, bn, lds, acc);
  int tid = threadIdx.x, w = tid >> 6, l = tid & 63;
  int lrow = l & 15, lg = l >> 4;
  int wm = w >> 1, wn = w & 1;
  #pragma unroll
  for (int n=0;n<4;++n){
    int gcol = bn*128 + wn*64 + n*16 + lrow;
    float bias = bias_p[gcol];
    #pragma unroll
    for (int m=0;m<4;++m){
      #pragma unroll
      for (int r=0;r<4;++r){
        int grow = bm*128 + wm*64 + m*16 + lg*4 + r;
        out[(size_t)grow*1024 + gcol] = acc[m][n][r] + bias;
      }
    }
  }
}

extern "C" void kernel_launch(void* const* d_in, const int* in_sizes, int n_in,
                              void* d_out, int out_size, void* d_ws, size_t ws_size,
                              hipStream_t stream){
  (void)in_sizes; (void)n_in; (void)out_size; (void)ws_size;
  const float* x     = (const float*)d_in[0];
  const float* w_qkv = (const float*)d_in[1];
  const float* w_out = (const float*)d_in[2];
  const float* b_out = (const float*)d_in[3];
  float* out = (float*)d_out;
  char* ws = (char*)d_ws;
  u16* xb    = (u16*)(ws + 0);
  u16* wqkvT = (u16*)(ws + 16777216);
  u16* woutT = (u16*)(ws + 23068672);
  u16* qw    = (u16*)(ws + 25165824);
  u16* kw    = (u16*)(ws + 41943040);
  u16* vtw   = (u16*)(ws + 58720256);
  u16* attn  = (u16*)(ws + 75497472);

  cvt_bf16_k<<<8192, 256, 0, stream>>>(x, xb);
  transpose_cvt_k<<<dim3(48,16), 256, 0, stream>>>(w_qkv, wqkvT, 1024, 3072);
  transpose_cvt_k<<<dim3(16,16), 256, 0, stream>>>(w_out, woutT, 1024, 1024);
  gemm_qkv_k<<<dim3(24,64), 256, 0, stream>>>(xb, wqkvT, qw, kw, vtw);
  attn_k<<<dim3(64,16), 256, 0, stream>>>(qw, kw, vtw, attn);
  gemm_out_k<<<dim3(8,64), 256, 0, stream>>>(attn, woutT, b_out, out);
}